// Round 5
// baseline (360.160 us; speedup 1.0000x reference)
//
#include <hip/hip_runtime.h>
#include <hip/hip_bf16.h>
#include <stdint.h>

// ---------------------------------------------------------------------------
// TernaryExpert: out = TL(gelu(TL(x, w_up)), w_down)
//   TL(x,w) = rmsnorm(x) @ ternary(w)^T
// M = 16384, d_model = 1024, d_ff = 4096. Output f32 [16384,1024].
// GEMM: 256x256 tile, BK=64, 8 waves (2Mx4N, 128x64/wave), 32x32x16 MFMA,
// 2 phases / 2 barriers per K-tile, counted vmcnt (never 0 mid-loop),
// double-buffered 128KB LDS, XOR-swizzled LDS, XCD-swizzled block ids.
// Phase 0: A rows [wm*128, +63] (quarters A0|A2) + all B; stages B0-3(t+1).
// Phase 1: A rows [wm*128+64, +63] (A1|A3), B reused in regs; stages A(t+1)
// in need order A0,A2,A1,A3. Mid-tile vmcnt(4)+barrier publishes A1,A3(t);
// tile-end vmcnt(2)+barrier publishes B0-3,A0,A2(t+1).
// ---------------------------------------------------------------------------

#define M_ROWS   16384
#define D_MODEL  1024
#define D_FF     4096
#define NW       (D_FF * D_MODEL)

typedef __attribute__((ext_vector_type(8))) short bf16x8;
typedef __attribute__((ext_vector_type(4))) float f32x4;
typedef __attribute__((ext_vector_type(16))) float f32x16;
typedef __attribute__((ext_vector_type(8))) unsigned short u16x8;

__device__ __forceinline__ unsigned short f2bf(float f) {
    unsigned u = __builtin_bit_cast(unsigned, f);
    u += 0x7FFFu + ((u >> 16) & 1u);          // RNE
    return (unsigned short)(u >> 16);
}
__device__ __forceinline__ float bf2f(unsigned short h) {
    return __builtin_bit_cast(float, ((unsigned)h) << 16);
}

__device__ __forceinline__ void gload_lds16(const void* g, void* l) {
    __builtin_amdgcn_global_load_lds(
        (const __attribute__((address_space(1))) void*)g,
        (__attribute__((address_space(3))) void*)l, 16, 0, 0);
}

__device__ __forceinline__ void barrier_raw() {
    asm volatile("" ::: "memory");
    __builtin_amdgcn_sched_barrier(0);
    __builtin_amdgcn_s_barrier();
    __builtin_amdgcn_sched_barrier(0);
    asm volatile("" ::: "memory");
}

#define LGKM0()  do { asm volatile("s_waitcnt lgkmcnt(0)" ::: "memory"); \
                      __builtin_amdgcn_sched_barrier(0); } while (0)
#define VMCNT4() do { asm volatile("s_waitcnt vmcnt(4)" ::: "memory"); \
                      __builtin_amdgcn_sched_barrier(0); } while (0)
#define VMCNT2() do { asm volatile("s_waitcnt vmcnt(2)" ::: "memory"); \
                      __builtin_amdgcn_sched_barrier(0); } while (0)
#define VMCNT0() do { asm volatile("s_waitcnt vmcnt(0)" ::: "memory"); \
                      __builtin_amdgcn_sched_barrier(0); } while (0)

__device__ __forceinline__ float gelu_fast(float v) {
    float w = v * v;
    float z = v * __builtin_fmaf(w, 0.07135481627f, 1.5957691216f);
    float e = __expf(-z);
    return v / (1.0f + e);
}

// ---------------------------------------------------------------------------
// aux kernels
// ---------------------------------------------------------------------------
__global__ __launch_bounds__(256) void absmean_reduce(const float* __restrict__ w,
                                                      double* __restrict__ asum) {
    const int n4 = NW / 4;
    float s = 0.f;
    const float4* w4 = (const float4*)w;
    for (int i = blockIdx.x * blockDim.x + threadIdx.x; i < n4;
         i += gridDim.x * blockDim.x) {
        float4 v = w4[i];
        s += fabsf(v.x) + fabsf(v.y) + fabsf(v.z) + fabsf(v.w);
    }
    #pragma unroll
    for (int off = 32; off > 0; off >>= 1) s += __shfl_down(s, off);
    __shared__ float sm[4];
    int lane = threadIdx.x & 63, wid = threadIdx.x >> 6;
    if (lane == 0) sm[wid] = s;
    __syncthreads();
    if (threadIdx.x == 0) {
        float t = sm[0] + sm[1] + sm[2] + sm[3];
        atomicAdd(asum, (double)t);
    }
}

__global__ __launch_bounds__(256) void quant_kernel(const float* __restrict__ w,
                                                    const double* __restrict__ asum,
                                                    unsigned short* __restrict__ wq) {
    float thr = (float)(0.5 * (*asum) * (1.0 / (double)NW));
    int i = blockIdx.x * blockDim.x + threadIdx.x;
    float4 v = ((const float4*)w)[i];
    ushort4 o;
    o.x = (fabsf(v.x) > thr) ? (v.x > 0.f ? 0x3F80 : 0xBF80) : 0;
    o.y = (fabsf(v.y) > thr) ? (v.y > 0.f ? 0x3F80 : 0xBF80) : 0;
    o.z = (fabsf(v.z) > thr) ? (v.z > 0.f ? 0x3F80 : 0xBF80) : 0;
    o.w = (fabsf(v.w) > thr) ? (v.w > 0.f ? 0x3F80 : 0xBF80) : 0;
    ((ushort4*)wq)[i] = o;
}

__global__ __launch_bounds__(256) void rmsnorm_x(const float* __restrict__ x,
                                                 unsigned short* __restrict__ xn) {
    const int row = blockIdx.x;
    const float4* xr = (const float4*)(x + (size_t)row * D_MODEL);
    float4 v = xr[threadIdx.x];
    float ss = v.x * v.x + v.y * v.y + v.z * v.z + v.w * v.w;
    #pragma unroll
    for (int off = 32; off > 0; off >>= 1) ss += __shfl_down(ss, off);
    __shared__ float sm[4];
    int lane = threadIdx.x & 63, wid = threadIdx.x >> 6;
    if (lane == 0) sm[wid] = ss;
    __syncthreads();
    float tot = sm[0] + sm[1] + sm[2] + sm[3];
    float s = 1.0f / (sqrtf(tot) * (1.0f / 32.0f) + 1e-8f);
    ushort4 o;
    o.x = f2bf(v.x * s); o.y = f2bf(v.y * s);
    o.z = f2bf(v.z * s); o.w = f2bf(v.w * s);
    ((ushort4*)(xn + (size_t)row * D_MODEL))[threadIdx.x] = o;
}

__global__ __launch_bounds__(256) void rowscale_h(const unsigned short* __restrict__ h,
                                                  float* __restrict__ rs) {
    const int row = blockIdx.x;
    const u16x8* hr = (const u16x8*)(h + (size_t)row * D_FF);
    u16x8 a = hr[threadIdx.x * 2 + 0];
    u16x8 b = hr[threadIdx.x * 2 + 1];
    float ss = 0.f;
    #pragma unroll
    for (int j = 0; j < 8; ++j) { float f = bf2f(a[j]); ss += f * f; }
    #pragma unroll
    for (int j = 0; j < 8; ++j) { float f = bf2f(b[j]); ss += f * f; }
    #pragma unroll
    for (int off = 32; off > 0; off >>= 1) ss += __shfl_down(ss, off);
    __shared__ float sm[4];
    int lane = threadIdx.x & 63, wid = threadIdx.x >> 6;
    if (lane == 0) sm[wid] = ss;
    __syncthreads();
    if (threadIdx.x == 0) {
        float tot = sm[0] + sm[1] + sm[2] + sm[3];
        rs[row] = 1.0f / (sqrtf(tot) * (1.0f / 64.0f) + 1e-8f);
    }
}

// ---------------------------------------------------------------------------
// GEMM: C[m][n] = sum_k A[m,k]*B[n,k]   (both K-contiguous)
// ---------------------------------------------------------------------------
template <int EPI, int KDIM, int NBLKN>
__global__ __launch_bounds__(512, 2) void gemm32(const unsigned short* __restrict__ A,
                                                 const unsigned short* __restrict__ B,
                                                 unsigned short* __restrict__ Cbf,
                                                 float* __restrict__ Cf,
                                                 const float* __restrict__ rowscale,
                                                 int nwg) {
    constexpr int BUFB = 65536;
    constexpr int NT = KDIM / 64;
    __shared__ char smem[2 * BUFB];

    const int tid = threadIdx.x;
    const int bid = blockIdx.x;
    const int swz = (bid & 7) * (nwg >> 3) + (bid >> 3);
    const uint m0 = (uint)(swz / NBLKN) * 256u;
    const uint n0 = (uint)(swz % NBLKN) * 256u;

    const int lane = tid & 63;
    const int wid  = tid >> 6;
    const int wm   = wid >> 2;                  // 0..1 -> 128-row slice
    const int wn   = wid & 3;                   // 0..3 -> 64-col slice
    const int l31  = lane & 31;
    const int hi   = lane >> 5;

    // staging geometry: thread covers row (tid>>3), 16B chunk (tid&7), pre-swizzled
    const uint rowBase = (uint)(tid >> 3);                        // 0..63
    const uint colE = (((uint)(tid & 7) << 4) ^ ((rowBase & 7u) << 4)) >> 1;
    const uint aBase = (m0 + rowBase) * (uint)KDIM + colE;
    const uint bBase = (n0 + rowBase) * (uint)KDIM + colE;
    const uint dstOff = (uint)tid * 16u;

    // fragment read offsets (bytes): row = l31 (+32-multiples), kstep s:
    // kbyte = s*32 + hi*16, XOR-swizzled with ((row&7)<<4) = ((lane&7)<<4)
    const uint xorv = ((uint)(lane & 7)) << 4;
    uint kbh[4];
    #pragma unroll
    for (int s = 0; s < 4; ++s) kbh[s] = ((uint)(s * 32 + hi * 16)) ^ xorv;
    uint baseA[2][2], baseB[2];
    #pragma unroll
    for (int R = 0; R < 2; ++R)
        #pragma unroll
        for (int r = 0; r < 2; ++r)
            baseA[R][r] = (uint)(wm * 128 + R * 64 + r * 32 + l31) * 128u;
    #pragma unroll
    for (int c = 0; c < 2; ++c)
        baseB[c] = 32768u + (uint)(wn * 64 + c * 32 + l31) * 128u;

    f32x16 acc[4][2];
    #pragma unroll
    for (int m = 0; m < 4; ++m)
        #pragma unroll
        for (int c = 0; c < 2; ++c)
            #pragma unroll
            for (int e = 0; e < 16; ++e) acc[m][c][e] = 0.f;

    // prologue: stage tile 0 in need order B0,B1,B2,B3,A0,A2,A1,A3
    {
        char* sb = smem;
        gload_lds16(B + bBase +   0u * KDIM, sb + 32768 +     0 + dstOff);
        gload_lds16(B + bBase +  64u * KDIM, sb + 32768 +  8192 + dstOff);
        gload_lds16(B + bBase + 128u * KDIM, sb + 32768 + 16384 + dstOff);
        gload_lds16(B + bBase + 192u * KDIM, sb + 32768 + 24576 + dstOff);
        gload_lds16(A + aBase +   0u * KDIM, sb +     0 + dstOff);   // A0
        gload_lds16(A + aBase + 128u * KDIM, sb + 16384 + dstOff);   // A2
        gload_lds16(A + aBase +  64u * KDIM, sb +  8192 + dstOff);   // A1
        gload_lds16(A + aBase + 192u * KDIM, sb + 24576 + dstOff);   // A3
    }
    VMCNT2();            // B0..B3, A0, A2 landed; A1, A3 in flight
    barrier_raw();

    #pragma unroll 1
    for (int t = 0; t < NT; ++t) {
        const char* cb = smem + (t & 1) * BUFB;
        char* sb = smem + ((t + 1) & 1) * BUFB;
        const uint tOff = (uint)(t + 1) * 64u;
        const bool doStage = (t + 1 < NT);
        bf16x8 af[2][4], bfr[2][4];

        // ---- phase 0: acc[0..1][*] — A rows wm*128..+63, all B, kk 0..3 ----
        #pragma unroll
        for (int r = 0; r < 2; ++r)
            #pragma unroll
            for (int s = 0; s < 4; ++s)
                af[r][s] = *(const bf16x8*)(cb + baseA[0][r] + kbh[s]);
        #pragma unroll
        for (int c = 0; c < 2; ++c)
            #pragma unroll
            for (int s = 0; s < 4; ++s)
                bfr[c][s] = *(const bf16x8*)(cb + baseB[c] + kbh[s]);
        if (doStage) {
            gload_lds16(B + bBase +   0u * KDIM + tOff, sb + 32768 +     0 + dstOff);
            gload_lds16(B + bBase +  64u * KDIM + tOff, sb + 32768 +  8192 + dstOff);
            gload_lds16(B + bBase + 128u * KDIM + tOff, sb + 32768 + 16384 + dstOff);
            gload_lds16(B + bBase + 192u * KDIM + tOff, sb + 32768 + 24576 + dstOff);
        }
        LGKM0();
        __builtin_amdgcn_s_setprio(1);
        #pragma unroll
        for (int s = 0; s < 4; ++s)
            #pragma unroll
            for (int r = 0; r < 2; ++r)
                #pragma unroll
                for (int c = 0; c < 2; ++c)
                    acc[r][c] = __builtin_amdgcn_mfma_f32_32x32x16_bf16(
                        af[r][s], bfr[c][s], acc[r][c], 0, 0, 0);
        __builtin_amdgcn_s_setprio(0);
        if (doStage) VMCNT4(); else VMCNT0();   // A1(t), A3(t) landed
        barrier_raw();

        // ---- phase 1: acc[2..3][*] — A rows wm*128+64..+127, B from regs ----
        #pragma unroll
        for (int r = 0; r < 2; ++r)
            #pragma unroll
            for (int s = 0; s < 4; ++s)
                af[r][s] = *(const bf16x8*)(cb + baseA[1][r] + kbh[s]);
        if (doStage) {
            gload_lds16(A + aBase +   0u * KDIM + tOff, sb +     0 + dstOff);  // A0
            gload_lds16(A + aBase + 128u * KDIM + tOff, sb + 16384 + dstOff);  // A2
            gload_lds16(A + aBase +  64u * KDIM + tOff, sb +  8192 + dstOff);  // A1
            gload_lds16(A + aBase + 192u * KDIM + tOff, sb + 24576 + dstOff);  // A3
        }
        LGKM0();
        __builtin_amdgcn_s_setprio(1);
        #pragma unroll
        for (int s = 0; s < 4; ++s)
            #pragma unroll
            for (int r = 0; r < 2; ++r)
                #pragma unroll
                for (int c = 0; c < 2; ++c)
                    acc[2 + r][c] = __builtin_amdgcn_mfma_f32_32x32x16_bf16(
                        af[r][s], bfr[c][s], acc[2 + r][c], 0, 0, 0);
        __builtin_amdgcn_s_setprio(0);
        if (doStage) VMCNT2();                  // B0..B3, A0, A2 of t+1 landed
        barrier_raw();
    }

    // epilogue: 32x32 C/D mapping: col = lane&31, row = (reg&3)+8*(reg>>2)+4*hi
    constexpr uint N = (uint)NBLKN * 256u;
    #pragma unroll
    for (int mf = 0; mf < 4; ++mf) {
        #pragma unroll
        for (int c = 0; c < 2; ++c) {
            const uint gc = n0 + (uint)(wn * 64 + c * 32 + l31);
            #pragma unroll
            for (int reg = 0; reg < 16; ++reg) {
                const uint gr = m0 + (uint)(wm * 128 + mf * 32 +
                                            (reg & 3) + 8 * (reg >> 2) + 4 * hi);
                float v = acc[mf][c][reg];
                if (EPI == 0) {
                    Cbf[gr * N + gc] = f2bf(gelu_fast(v));
                } else {
                    Cf[gr * N + gc] = v * rowscale[gr];
                }
            }
        }
    }
}

// ---------------------------------------------------------------------------
extern "C" void kernel_launch(void* const* d_in, const int* in_sizes, int n_in,
                              void* d_out, int out_size, void* d_ws, size_t ws_size,
                              hipStream_t stream) {
    const float* x    = (const float*)d_in[0];
    const float* w_up = (const float*)d_in[1];
    const float* w_dn = (const float*)d_in[2];
    float* out = (float*)d_out;

    uint8_t* ws = (uint8_t*)d_ws;
    unsigned short* h   = (unsigned short*)(ws);                       // 128 MB
    unsigned short* xn  = (unsigned short*)(ws + 134217728);           // 32 MB
    unsigned short* wqu = (unsigned short*)(ws + 134217728 + 33554432);
    unsigned short* wqd = (unsigned short*)(ws + 134217728 + 33554432 + 8388608);
    float*  rs   = (float*)(ws + 134217728 + 33554432 + 2 * 8388608);
    double* alph = (double*)(ws + 134217728 + 33554432 + 2 * 8388608 + 65536);

    hipMemsetAsync(alph, 0, 16, stream);

    absmean_reduce<<<256, 256, 0, stream>>>(w_up, alph + 0);
    absmean_reduce<<<256, 256, 0, stream>>>(w_dn, alph + 1);
    quant_kernel<<<NW / 1024, 256, 0, stream>>>(w_up, alph + 0, wqu);
    quant_kernel<<<NW / 1024, 256, 0, stream>>>(w_dn, alph + 1, wqd);
    rmsnorm_x<<<M_ROWS, 256, 0, stream>>>(x, xn);

    // L1: h = gelu(xn @ wqu^T)  [16384 x 4096], K=1024 -> 64x16 = 1024 blocks
    gemm32<0, D_MODEL, 16><<<1024, 512, 0, stream>>>(
        xn, wqu, h, nullptr, nullptr, 1024);

    rowscale_h<<<M_ROWS, 256, 0, stream>>>(h, rs);

    // L2: out = (h @ wqd^T) * rs[m]  [16384 x 1024], K=4096 -> 64x4 = 256 blocks
    gemm32<1, D_FF, 4><<<256, 512, 0, stream>>>(
        h, wqd, nullptr, out, rs, 256);
}

// Round 6
// 331.845 us; speedup vs baseline: 1.0853x; 1.0853x over previous
//
#include <hip/hip_runtime.h>
#include <hip/hip_bf16.h>
#include <stdint.h>

// ---------------------------------------------------------------------------
// TernaryExpert: out = TL(gelu(TL(x, w_up)), w_down)
//   TL(x,w) = rmsnorm(x) @ ternary(w)^T
// M = 16384, d_model = 1024, d_ff = 4096. Output f32 [16384,1024].
// GEMM: 256x256 tile, BK=64, 8 waves (2Mx4N, 128x64/wave), 16x16x32 MFMA
// (R4's conflict-free read pattern), 2 phases / 2 barriers per K-tile,
// counted vmcnt (never 0 mid-loop), double-buffered 128KB LDS, XOR swizzle.
// Staging: ph0 issues {B0..B3, A0, A2}(t+1); ph1 issues {A1, A3}(t+1).
// Mid-tile vmcnt(6) publishes A1,A3(t); tile-end vmcnt(2) publishes
// B0..B3,A0,A2(t+1). Every load gets >= 1 full phase to land.
// ---------------------------------------------------------------------------

#define M_ROWS   16384
#define D_MODEL  1024
#define D_FF     4096
#define NW       (D_FF * D_MODEL)

typedef __attribute__((ext_vector_type(8))) short bf16x8;
typedef __attribute__((ext_vector_type(4))) float f32x4;
typedef __attribute__((ext_vector_type(8))) unsigned short u16x8;

__device__ __forceinline__ unsigned short f2bf(float f) {
    unsigned u = __builtin_bit_cast(unsigned, f);
    u += 0x7FFFu + ((u >> 16) & 1u);          // RNE
    return (unsigned short)(u >> 16);
}
__device__ __forceinline__ float bf2f(unsigned short h) {
    return __builtin_bit_cast(float, ((unsigned)h) << 16);
}

__device__ __forceinline__ void gload_lds16(const void* g, void* l) {
    __builtin_amdgcn_global_load_lds(
        (const __attribute__((address_space(1))) void*)g,
        (__attribute__((address_space(3))) void*)l, 16, 0, 0);
}

__device__ __forceinline__ void barrier_raw() {
    asm volatile("" ::: "memory");
    __builtin_amdgcn_sched_barrier(0);
    __builtin_amdgcn_s_barrier();
    __builtin_amdgcn_sched_barrier(0);
    asm volatile("" ::: "memory");
}

#define LGKM0()  do { asm volatile("s_waitcnt lgkmcnt(0)" ::: "memory"); \
                      __builtin_amdgcn_sched_barrier(0); } while (0)
#define VMCNT6() do { asm volatile("s_waitcnt vmcnt(6)" ::: "memory"); \
                      __builtin_amdgcn_sched_barrier(0); } while (0)
#define VMCNT2() do { asm volatile("s_waitcnt vmcnt(2)" ::: "memory"); \
                      __builtin_amdgcn_sched_barrier(0); } while (0)
#define VMCNT0() do { asm volatile("s_waitcnt vmcnt(0)" ::: "memory"); \
                      __builtin_amdgcn_sched_barrier(0); } while (0)

__device__ __forceinline__ float gelu_fast(float v) {
    float w = v * v;
    float z = v * __builtin_fmaf(w, 0.07135481627f, 1.5957691216f);
    float e = __expf(-z);
    return v / (1.0f + e);
}

// ---------------------------------------------------------------------------
// aux kernels
// ---------------------------------------------------------------------------
__global__ __launch_bounds__(256) void absmean_reduce(const float* __restrict__ w,
                                                      double* __restrict__ asum) {
    const int n4 = NW / 4;
    float s = 0.f;
    const float4* w4 = (const float4*)w;
    for (int i = blockIdx.x * blockDim.x + threadIdx.x; i < n4;
         i += gridDim.x * blockDim.x) {
        float4 v = w4[i];
        s += fabsf(v.x) + fabsf(v.y) + fabsf(v.z) + fabsf(v.w);
    }
    #pragma unroll
    for (int off = 32; off > 0; off >>= 1) s += __shfl_down(s, off);
    __shared__ float sm[4];
    int lane = threadIdx.x & 63, wid = threadIdx.x >> 6;
    if (lane == 0) sm[wid] = s;
    __syncthreads();
    if (threadIdx.x == 0) {
        float t = sm[0] + sm[1] + sm[2] + sm[3];
        atomicAdd(asum, (double)t);
    }
}

__global__ __launch_bounds__(256) void quant_kernel(const float* __restrict__ w,
                                                    const double* __restrict__ asum,
                                                    unsigned short* __restrict__ wq) {
    float thr = (float)(0.5 * (*asum) * (1.0 / (double)NW));
    int i = blockIdx.x * blockDim.x + threadIdx.x;
    float4 v = ((const float4*)w)[i];
    ushort4 o;
    o.x = (fabsf(v.x) > thr) ? (v.x > 0.f ? 0x3F80 : 0xBF80) : 0;
    o.y = (fabsf(v.y) > thr) ? (v.y > 0.f ? 0x3F80 : 0xBF80) : 0;
    o.z = (fabsf(v.z) > thr) ? (v.z > 0.f ? 0x3F80 : 0xBF80) : 0;
    o.w = (fabsf(v.w) > thr) ? (v.w > 0.f ? 0x3F80 : 0xBF80) : 0;
    ((ushort4*)wq)[i] = o;
}

__global__ __launch_bounds__(256) void rmsnorm_x(const float* __restrict__ x,
                                                 unsigned short* __restrict__ xn) {
    const int row = blockIdx.x;
    const float4* xr = (const float4*)(x + (size_t)row * D_MODEL);
    float4 v = xr[threadIdx.x];
    float ss = v.x * v.x + v.y * v.y + v.z * v.z + v.w * v.w;
    #pragma unroll
    for (int off = 32; off > 0; off >>= 1) ss += __shfl_down(ss, off);
    __shared__ float sm[4];
    int lane = threadIdx.x & 63, wid = threadIdx.x >> 6;
    if (lane == 0) sm[wid] = ss;
    __syncthreads();
    float tot = sm[0] + sm[1] + sm[2] + sm[3];
    float s = 1.0f / (sqrtf(tot) * (1.0f / 32.0f) + 1e-8f);
    ushort4 o;
    o.x = f2bf(v.x * s); o.y = f2bf(v.y * s);
    o.z = f2bf(v.z * s); o.w = f2bf(v.w * s);
    ((ushort4*)(xn + (size_t)row * D_MODEL))[threadIdx.x] = o;
}

__global__ __launch_bounds__(256) void rowscale_h(const unsigned short* __restrict__ h,
                                                  float* __restrict__ rs) {
    const int row = blockIdx.x;
    const u16x8* hr = (const u16x8*)(h + (size_t)row * D_FF);
    u16x8 a = hr[threadIdx.x * 2 + 0];
    u16x8 b = hr[threadIdx.x * 2 + 1];
    float ss = 0.f;
    #pragma unroll
    for (int j = 0; j < 8; ++j) { float f = bf2f(a[j]); ss += f * f; }
    #pragma unroll
    for (int j = 0; j < 8; ++j) { float f = bf2f(b[j]); ss += f * f; }
    #pragma unroll
    for (int off = 32; off > 0; off >>= 1) ss += __shfl_down(ss, off);
    __shared__ float sm[4];
    int lane = threadIdx.x & 63, wid = threadIdx.x >> 6;
    if (lane == 0) sm[wid] = ss;
    __syncthreads();
    if (threadIdx.x == 0) {
        float tot = sm[0] + sm[1] + sm[2] + sm[3];
        rs[row] = 1.0f / (sqrtf(tot) * (1.0f / 64.0f) + 1e-8f);
    }
}

// ---------------------------------------------------------------------------
// GEMM: C[m][n] = sum_k A[m,k]*B[n,k]   (both K-contiguous)
// ---------------------------------------------------------------------------
template <int EPI, int KDIM, int NBLKN>
__global__ __launch_bounds__(512, 2) void gemm2p(const unsigned short* __restrict__ A,
                                                 const unsigned short* __restrict__ B,
                                                 unsigned short* __restrict__ Cbf,
                                                 float* __restrict__ Cf,
                                                 const float* __restrict__ rowscale,
                                                 int nwg) {
    constexpr int BUFB = 65536;
    constexpr int NT = KDIM / 64;
    __shared__ char smem[2 * BUFB];

    const int tid = threadIdx.x;
    const int bid = blockIdx.x;
    const int swz = (bid & 7) * (nwg >> 3) + (bid >> 3);
    const uint m0 = (uint)(swz / NBLKN) * 256u;
    const uint n0 = (uint)(swz % NBLKN) * 256u;

    const int lane = tid & 63;
    const int wid  = tid >> 6;
    const int wm   = wid >> 2;                  // 0..1 -> 128-row slice
    const int wn   = wid & 3;                   // 0..3 -> 64-col slice
    const int lr   = lane & 15;
    const int lk   = lane >> 4;

    // staging geometry: thread covers row (tid>>3), 16B chunk (tid&7), pre-swizzled
    const uint rowBase = (uint)(tid >> 3);                        // 0..63
    const uint colE = (((uint)(tid & 7) << 4) ^ ((rowBase & 7u) << 4)) >> 1;
    const uint aBase = (m0 + rowBase) * (uint)KDIM + colE;
    const uint bBase = (n0 + rowBase) * (uint)KDIM + colE;
    const uint dstOff = (uint)tid * 16u;

    // fragment read offsets (bytes), R4's conflict-free 16x16 pattern
    const uint xorv = ((uint)(lr & 7)) << 4;
    const uint kb0 = (((uint)lk << 4)      ) ^ xorv;
    const uint kb1 = (((uint)lk << 4) | 64u) ^ xorv;
    uint offA[8], offB[4];
    #pragma unroll
    for (int i = 0; i < 8; ++i)
        offA[i] = (uint)(wm * 128 + i * 16 + lr) * 128u;
    #pragma unroll
    for (int i = 0; i < 4; ++i)
        offB[i] = 32768u + (uint)(wn * 64 + i * 16 + lr) * 128u;

    f32x4 acc[8][4];
    #pragma unroll
    for (int mi = 0; mi < 8; ++mi)
        #pragma unroll
        for (int ni = 0; ni < 4; ++ni)
            acc[mi][ni] = (f32x4){0.f, 0.f, 0.f, 0.f};

    // prologue: stage tile 0 in need order B0,B1,B2,B3,A0,A2,A1,A3
    {
        char* sb = smem;
        gload_lds16(B + bBase +   0u * KDIM, sb + 32768 +     0 + dstOff);
        gload_lds16(B + bBase +  64u * KDIM, sb + 32768 +  8192 + dstOff);
        gload_lds16(B + bBase + 128u * KDIM, sb + 32768 + 16384 + dstOff);
        gload_lds16(B + bBase + 192u * KDIM, sb + 32768 + 24576 + dstOff);
        gload_lds16(A + aBase +   0u * KDIM, sb +     0 + dstOff);   // A0
        gload_lds16(A + aBase + 128u * KDIM, sb + 16384 + dstOff);   // A2
        gload_lds16(A + aBase +  64u * KDIM, sb +  8192 + dstOff);   // A1
        gload_lds16(A + aBase + 192u * KDIM, sb + 24576 + dstOff);   // A3
    }
    VMCNT2();            // B0..B3, A0, A2 landed; A1, A3 in flight
    barrier_raw();

    #pragma unroll 1
    for (int t = 0; t < NT; ++t) {
        const char* cb = smem + (t & 1) * BUFB;
        char* sb = smem + ((t + 1) & 1) * BUFB;
        const uint tOff = (uint)(t + 1) * 64u;
        const bool doStage = (t + 1 < NT);
        bf16x8 av0[4], av1[4], bv0[4], bv1[4];

        // ---- phase 0: acc[0..3] — A rows wm*128..+63, both k-halves ----
        #pragma unroll
        for (int i = 0; i < 4; ++i) {
            av0[i] = *(const bf16x8*)(cb + offA[i] + kb0);
            av1[i] = *(const bf16x8*)(cb + offA[i] + kb1);
        }
        #pragma unroll
        for (int i = 0; i < 4; ++i) {
            bv0[i] = *(const bf16x8*)(cb + offB[i] + kb0);
            bv1[i] = *(const bf16x8*)(cb + offB[i] + kb1);
        }
        if (doStage) {
            gload_lds16(B + bBase +   0u * KDIM + tOff, sb + 32768 +     0 + dstOff);
            gload_lds16(B + bBase +  64u * KDIM + tOff, sb + 32768 +  8192 + dstOff);
            gload_lds16(B + bBase + 128u * KDIM + tOff, sb + 32768 + 16384 + dstOff);
            gload_lds16(B + bBase + 192u * KDIM + tOff, sb + 32768 + 24576 + dstOff);
            gload_lds16(A + aBase +   0u * KDIM + tOff, sb +     0 + dstOff);  // A0
            gload_lds16(A + aBase + 128u * KDIM + tOff, sb + 16384 + dstOff);  // A2
        }
        LGKM0();
        __builtin_amdgcn_s_setprio(1);
        #pragma unroll
        for (int mi = 0; mi < 4; ++mi)
            #pragma unroll
            for (int ni = 0; ni < 4; ++ni)
                acc[mi][ni] = __builtin_amdgcn_mfma_f32_16x16x32_bf16(
                    av0[mi], bv0[ni], acc[mi][ni], 0, 0, 0);
        #pragma unroll
        for (int mi = 0; mi < 4; ++mi)
            #pragma unroll
            for (int ni = 0; ni < 4; ++ni)
                acc[mi][ni] = __builtin_amdgcn_mfma_f32_16x16x32_bf16(
                    av1[mi], bv1[ni], acc[mi][ni], 0, 0, 0);
        __builtin_amdgcn_s_setprio(0);
        if (doStage) VMCNT6(); else VMCNT0();   // A1(t), A3(t) landed
        barrier_raw();

        // ---- phase 1: acc[4..7] — A rows wm*128+64..+127, B from regs ----
        #pragma unroll
        for (int i = 0; i < 4; ++i) {
            av0[i] = *(const bf16x8*)(cb + offA[4 + i] + kb0);
            av1[i] = *(const bf16x8*)(cb + offA[4 + i] + kb1);
        }
        if (doStage) {
            gload_lds16(A + aBase +  64u * KDIM + tOff, sb +  8192 + dstOff);  // A1
            gload_lds16(A + aBase + 192u * KDIM + tOff, sb + 24576 + dstOff);  // A3
        }
        LGKM0();
        __builtin_amdgcn_s_setprio(1);
        #pragma unroll
        for (int mi = 0; mi < 4; ++mi)
            #pragma unroll
            for (int ni = 0; ni < 4; ++ni)
                acc[4 + mi][ni] = __builtin_amdgcn_mfma_f32_16x16x32_bf16(
                    av0[mi], bv0[ni], acc[4 + mi][ni], 0, 0, 0);
        #pragma unroll
        for (int mi = 0; mi < 4; ++mi)
            #pragma unroll
            for (int ni = 0; ni < 4; ++ni)
                acc[4 + mi][ni] = __builtin_amdgcn_mfma_f32_16x16x32_bf16(
                    av1[mi], bv1[ni], acc[4 + mi][ni], 0, 0, 0);
        __builtin_amdgcn_s_setprio(0);
        if (doStage) VMCNT2();                  // B0..B3, A0, A2 of t+1 landed
        barrier_raw();
    }

    // epilogue: C/D frag mapping col = lane&15, row = (lane>>4)*4 + reg
    constexpr uint N = (uint)NBLKN * 256u;
    #pragma unroll
    for (int mi = 0; mi < 8; ++mi) {
        #pragma unroll
        for (int j = 0; j < 4; ++j) {
            const uint gr = m0 + (uint)(wm * 128 + mi * 16 + lk * 4 + j);
            float s = 0.f;
            if (EPI == 1) s = rowscale[gr];
            #pragma unroll
            for (int ni = 0; ni < 4; ++ni) {
                const uint gc = n0 + (uint)(wn * 64 + ni * 16 + lr);
                float v = acc[mi][ni][j];
                if (EPI == 0) {
                    Cbf[gr * N + gc] = f2bf(gelu_fast(v));
                } else {
                    Cf[gr * N + gc] = v * s;
                }
            }
        }
    }
}

// ---------------------------------------------------------------------------
extern "C" void kernel_launch(void* const* d_in, const int* in_sizes, int n_in,
                              void* d_out, int out_size, void* d_ws, size_t ws_size,
                              hipStream_t stream) {
    const float* x    = (const float*)d_in[0];
    const float* w_up = (const float*)d_in[1];
    const float* w_dn = (const float*)d_in[2];
    float* out = (float*)d_out;

    uint8_t* ws = (uint8_t*)d_ws;
    unsigned short* h   = (unsigned short*)(ws);                       // 128 MB
    unsigned short* xn  = (unsigned short*)(ws + 134217728);           // 32 MB
    unsigned short* wqu = (unsigned short*)(ws + 134217728 + 33554432);
    unsigned short* wqd = (unsigned short*)(ws + 134217728 + 33554432 + 8388608);
    float*  rs   = (float*)(ws + 134217728 + 33554432 + 2 * 8388608);
    double* alph = (double*)(ws + 134217728 + 33554432 + 2 * 8388608 + 65536);

    hipMemsetAsync(alph, 0, 16, stream);

    absmean_reduce<<<256, 256, 0, stream>>>(w_up, alph + 0);
    absmean_reduce<<<256, 256, 0, stream>>>(w_dn, alph + 1);
    quant_kernel<<<NW / 1024, 256, 0, stream>>>(w_up, alph + 0, wqu);
    quant_kernel<<<NW / 1024, 256, 0, stream>>>(w_dn, alph + 1, wqd);
    rmsnorm_x<<<M_ROWS, 256, 0, stream>>>(x, xn);

    // L1: h = gelu(xn @ wqu^T)  [16384 x 4096], K=1024 -> 64x16 = 1024 blocks
    gemm2p<0, D_MODEL, 16><<<1024, 512, 0, stream>>>(
        xn, wqu, h, nullptr, nullptr, 1024);

    rowscale_h<<<M_ROWS, 256, 0, stream>>>(h, rs);

    // L2: out = (h @ wqd^T) * rs[m]  [16384 x 1024], K=4096 -> 64x4 = 256 blocks
    gemm2p<1, D_FF, 4><<<256, 512, 0, stream>>>(
        h, wqd, nullptr, out, rs, 256);
}

// Round 7
// 327.240 us; speedup vs baseline: 1.1006x; 1.0141x over previous
//
#include <hip/hip_runtime.h>
#include <hip/hip_bf16.h>
#include <stdint.h>

// ---------------------------------------------------------------------------
// TernaryExpert: out = TL(gelu(TL(x, w_up)), w_down)
//   TL(x,w) = rmsnorm(x) @ ternary(w)^T
// M = 16384, d_model = 1024, d_ff = 4096. Output f32 [16384,1024].
// GEMM: 256x256, BK=64, 8 waves (2Mx4N, 128x64/wave), 16x16x32 MFMA,
// m201-style 4 phases/K-tile: reads issued BEFORE each barrier, lgkm0 AFTER
// (read latency hides under barrier wait), 16 MFMA per phase, counted vmcnt.
// Publishes: barrier2 -> A1,A3(t); barrier4 (=tile start t+1) -> B0-3,A0,A2.
// ---------------------------------------------------------------------------

#define M_ROWS   16384
#define D_MODEL  1024
#define D_FF     4096
#define NW       (D_FF * D_MODEL)

typedef __attribute__((ext_vector_type(8))) short bf16x8;
typedef __attribute__((ext_vector_type(4))) float f32x4;
typedef __attribute__((ext_vector_type(8))) unsigned short u16x8;

__device__ __forceinline__ unsigned short f2bf(float f) {
    unsigned u = __builtin_bit_cast(unsigned, f);
    u += 0x7FFFu + ((u >> 16) & 1u);          // RNE
    return (unsigned short)(u >> 16);
}
__device__ __forceinline__ float bf2f(unsigned short h) {
    return __builtin_bit_cast(float, ((unsigned)h) << 16);
}

__device__ __forceinline__ void gload_lds16(const void* g, void* l) {
    __builtin_amdgcn_global_load_lds(
        (const __attribute__((address_space(1))) void*)g,
        (__attribute__((address_space(3))) void*)l, 16, 0, 0);
}

__device__ __forceinline__ void barrier_raw() {
    asm volatile("" ::: "memory");
    __builtin_amdgcn_sched_barrier(0);
    __builtin_amdgcn_s_barrier();
    __builtin_amdgcn_sched_barrier(0);
    asm volatile("" ::: "memory");
}

#define LGKM0()  do { asm volatile("s_waitcnt lgkmcnt(0)" ::: "memory"); \
                      __builtin_amdgcn_sched_barrier(0); } while (0)
#define VMCNT4() do { asm volatile("s_waitcnt vmcnt(4)" ::: "memory"); \
                      __builtin_amdgcn_sched_barrier(0); } while (0)
#define VMCNT2() do { asm volatile("s_waitcnt vmcnt(2)" ::: "memory"); \
                      __builtin_amdgcn_sched_barrier(0); } while (0)
#define VMCNT0() do { asm volatile("s_waitcnt vmcnt(0)" ::: "memory"); \
                      __builtin_amdgcn_sched_barrier(0); } while (0)

__device__ __forceinline__ float gelu_fast(float v) {
    float w = v * v;
    float z = v * __builtin_fmaf(w, 0.07135481627f, 1.5957691216f);
    float e = __expf(-z);
    return v / (1.0f + e);
}

// ---------------------------------------------------------------------------
// aux kernels
// ---------------------------------------------------------------------------
__global__ __launch_bounds__(256) void absmean_reduce(const float* __restrict__ w,
                                                      double* __restrict__ asum) {
    const int n4 = NW / 4;
    float s = 0.f;
    const float4* w4 = (const float4*)w;
    for (int i = blockIdx.x * blockDim.x + threadIdx.x; i < n4;
         i += gridDim.x * blockDim.x) {
        float4 v = w4[i];
        s += fabsf(v.x) + fabsf(v.y) + fabsf(v.z) + fabsf(v.w);
    }
    #pragma unroll
    for (int off = 32; off > 0; off >>= 1) s += __shfl_down(s, off);
    __shared__ float sm[4];
    int lane = threadIdx.x & 63, wid = threadIdx.x >> 6;
    if (lane == 0) sm[wid] = s;
    __syncthreads();
    if (threadIdx.x == 0) {
        float t = sm[0] + sm[1] + sm[2] + sm[3];
        atomicAdd(asum, (double)t);
    }
}

__global__ __launch_bounds__(256) void quant_kernel(const float* __restrict__ w,
                                                    const double* __restrict__ asum,
                                                    unsigned short* __restrict__ wq) {
    float thr = (float)(0.5 * (*asum) * (1.0 / (double)NW));
    int i = blockIdx.x * blockDim.x + threadIdx.x;
    float4 v = ((const float4*)w)[i];
    ushort4 o;
    o.x = (fabsf(v.x) > thr) ? (v.x > 0.f ? 0x3F80 : 0xBF80) : 0;
    o.y = (fabsf(v.y) > thr) ? (v.y > 0.f ? 0x3F80 : 0xBF80) : 0;
    o.z = (fabsf(v.z) > thr) ? (v.z > 0.f ? 0x3F80 : 0xBF80) : 0;
    o.w = (fabsf(v.w) > thr) ? (v.w > 0.f ? 0x3F80 : 0xBF80) : 0;
    ((ushort4*)wq)[i] = o;
}

__global__ __launch_bounds__(256) void rmsnorm_x(const float* __restrict__ x,
                                                 unsigned short* __restrict__ xn) {
    const int row = blockIdx.x;
    const float4* xr = (const float4*)(x + (size_t)row * D_MODEL);
    float4 v = xr[threadIdx.x];
    float ss = v.x * v.x + v.y * v.y + v.z * v.z + v.w * v.w;
    #pragma unroll
    for (int off = 32; off > 0; off >>= 1) ss += __shfl_down(ss, off);
    __shared__ float sm[4];
    int lane = threadIdx.x & 63, wid = threadIdx.x >> 6;
    if (lane == 0) sm[wid] = ss;
    __syncthreads();
    float tot = sm[0] + sm[1] + sm[2] + sm[3];
    float s = 1.0f / (sqrtf(tot) * (1.0f / 32.0f) + 1e-8f);
    ushort4 o;
    o.x = f2bf(v.x * s); o.y = f2bf(v.y * s);
    o.z = f2bf(v.z * s); o.w = f2bf(v.w * s);
    ((ushort4*)(xn + (size_t)row * D_MODEL))[threadIdx.x] = o;
}

__global__ __launch_bounds__(256) void rowscale_h(const unsigned short* __restrict__ h,
                                                  float* __restrict__ rs) {
    const int row = blockIdx.x;
    const u16x8* hr = (const u16x8*)(h + (size_t)row * D_FF);
    u16x8 a = hr[threadIdx.x * 2 + 0];
    u16x8 b = hr[threadIdx.x * 2 + 1];
    float ss = 0.f;
    #pragma unroll
    for (int j = 0; j < 8; ++j) { float f = bf2f(a[j]); ss += f * f; }
    #pragma unroll
    for (int j = 0; j < 8; ++j) { float f = bf2f(b[j]); ss += f * f; }
    #pragma unroll
    for (int off = 32; off > 0; off >>= 1) ss += __shfl_down(ss, off);
    __shared__ float sm[4];
    int lane = threadIdx.x & 63, wid = threadIdx.x >> 6;
    if (lane == 0) sm[wid] = ss;
    __syncthreads();
    if (threadIdx.x == 0) {
        float tot = sm[0] + sm[1] + sm[2] + sm[3];
        rs[row] = 1.0f / (sqrtf(tot) * (1.0f / 64.0f) + 1e-8f);
    }
}

// ---------------------------------------------------------------------------
// GEMM: C[m][n] = sum_k A[m,k]*B[n,k]   (both K-contiguous)
// ---------------------------------------------------------------------------
template <int EPI, int KDIM, int NBLKN>
__global__ __launch_bounds__(512, 2) void gemm4p(const unsigned short* __restrict__ A,
                                                 const unsigned short* __restrict__ B,
                                                 unsigned short* __restrict__ Cbf,
                                                 float* __restrict__ Cf,
                                                 const float* __restrict__ rowscale,
                                                 int nwg) {
    constexpr int BUFB = 65536;
    constexpr int NT = KDIM / 64;
    __shared__ char smem[2 * BUFB];

    const int tid = threadIdx.x;
    const int bid = blockIdx.x;
    const int swz = (bid & 7) * (nwg >> 3) + (bid >> 3);
    const uint m0 = (uint)(swz / NBLKN) * 256u;
    const uint n0 = (uint)(swz % NBLKN) * 256u;

    const int lane = tid & 63;
    const int wid  = tid >> 6;
    const int wm   = wid >> 2;                  // 0..1 -> 128-row slice
    const int wn   = wid & 3;                   // 0..3 -> 64-col slice
    const int lr   = lane & 15;
    const int lk   = lane >> 4;

    // staging geometry: thread covers row (tid>>3), 16B chunk (tid&7), pre-swizzled
    const uint rowBase = (uint)(tid >> 3);                        // 0..63
    const uint colE = (((uint)(tid & 7) << 4) ^ ((rowBase & 7u) << 4)) >> 1;
    const uint aBase = (m0 + rowBase) * (uint)KDIM + colE;
    const uint bBase = (n0 + rowBase) * (uint)KDIM + colE;
    const uint dstOff = (uint)tid * 16u;

    // fragment read offsets (bytes), R4's conflict-free 16x16 pattern
    const uint xorv = ((uint)(lr & 7)) << 4;
    const uint kb0 = (((uint)lk << 4)      ) ^ xorv;
    const uint kb1 = (((uint)lk << 4) | 64u) ^ xorv;
    uint offA[8], offB[4];
    #pragma unroll
    for (int i = 0; i < 8; ++i)
        offA[i] = (uint)(wm * 128 + i * 16 + lr) * 128u;
    #pragma unroll
    for (int i = 0; i < 4; ++i)
        offB[i] = 32768u + (uint)(wn * 64 + i * 16 + lr) * 128u;

    f32x4 acc[8][4];
    #pragma unroll
    for (int mi = 0; mi < 8; ++mi)
        #pragma unroll
        for (int ni = 0; ni < 4; ++ni)
            acc[mi][ni] = (f32x4){0.f, 0.f, 0.f, 0.f};

    // prologue: stage tile 0 in need order B0,B1,B2,B3,A0,A2,A1,A3
    {
        char* sb = smem;
        gload_lds16(B + bBase +   0u * KDIM, sb + 32768 +     0 + dstOff);
        gload_lds16(B + bBase +  64u * KDIM, sb + 32768 +  8192 + dstOff);
        gload_lds16(B + bBase + 128u * KDIM, sb + 32768 + 16384 + dstOff);
        gload_lds16(B + bBase + 192u * KDIM, sb + 32768 + 24576 + dstOff);
        gload_lds16(A + aBase +   0u * KDIM, sb +     0 + dstOff);   // A0
        gload_lds16(A + aBase + 128u * KDIM, sb + 16384 + dstOff);   // A2
        gload_lds16(A + aBase +  64u * KDIM, sb +  8192 + dstOff);   // A1
        gload_lds16(A + aBase + 192u * KDIM, sb + 24576 + dstOff);   // A3
    }
    VMCNT2();            // B0..B3, A0, A2 landed; A1, A3 in flight
    barrier_raw();

    #pragma unroll 1
    for (int t = 0; t < NT; ++t) {
        const char* cb = smem + (t & 1) * BUFB;
        char* sb = smem + ((t + 1) & 1) * BUFB;
        const uint tOff = (uint)(t + 1) * 64u;
        const bool doStage = (t + 1 < NT);
        bf16x8 av[4], bv0[4], bv1[4];

        // ---- P1: A-h0 kh0 + B kh0 reads; stage B0,B1; bar; 16 MFMA ----
        #pragma unroll
        for (int i = 0; i < 4; ++i) av[i]  = *(const bf16x8*)(cb + offA[i] + kb0);
        #pragma unroll
        for (int i = 0; i < 4; ++i) bv0[i] = *(const bf16x8*)(cb + offB[i] + kb0);
        if (doStage) {
            gload_lds16(B + bBase +   0u * KDIM + tOff, sb + 32768 +     0 + dstOff);
            gload_lds16(B + bBase +  64u * KDIM + tOff, sb + 32768 +  8192 + dstOff);
        }
        barrier_raw();
        LGKM0();
        __builtin_amdgcn_s_setprio(1);
        #pragma unroll
        for (int mi = 0; mi < 4; ++mi)
            #pragma unroll
            for (int ni = 0; ni < 4; ++ni)
                acc[mi][ni] = __builtin_amdgcn_mfma_f32_16x16x32_bf16(
                    av[mi], bv0[ni], acc[mi][ni], 0, 0, 0);
        __builtin_amdgcn_s_setprio(0);

        // ---- P2: A-h0 kh1 + B kh1 reads; stage B2,B3; vmcnt(4); bar
        //      (publishes A1,A3(t)); 16 MFMA ----
        #pragma unroll
        for (int i = 0; i < 4; ++i) av[i]  = *(const bf16x8*)(cb + offA[i] + kb1);
        #pragma unroll
        for (int i = 0; i < 4; ++i) bv1[i] = *(const bf16x8*)(cb + offB[i] + kb1);
        if (doStage) {
            gload_lds16(B + bBase + 128u * KDIM + tOff, sb + 32768 + 16384 + dstOff);
            gload_lds16(B + bBase + 192u * KDIM + tOff, sb + 32768 + 24576 + dstOff);
            VMCNT4();
        } else {
            VMCNT0();
        }
        barrier_raw();
        LGKM0();
        __builtin_amdgcn_s_setprio(1);
        #pragma unroll
        for (int mi = 0; mi < 4; ++mi)
            #pragma unroll
            for (int ni = 0; ni < 4; ++ni)
                acc[mi][ni] = __builtin_amdgcn_mfma_f32_16x16x32_bf16(
                    av[mi], bv1[ni], acc[mi][ni], 0, 0, 0);
        __builtin_amdgcn_s_setprio(0);

        // ---- P3: A-h1 kh0 reads (B kh0 reg-reused); stage A0,A2; bar; 16 MFMA ----
        #pragma unroll
        for (int i = 0; i < 4; ++i) av[i] = *(const bf16x8*)(cb + offA[4 + i] + kb0);
        if (doStage) {
            gload_lds16(A + aBase +   0u * KDIM + tOff, sb +     0 + dstOff);  // A0
            gload_lds16(A + aBase + 128u * KDIM + tOff, sb + 16384 + dstOff);  // A2
        }
        barrier_raw();
        LGKM0();
        __builtin_amdgcn_s_setprio(1);
        #pragma unroll
        for (int mi = 0; mi < 4; ++mi)
            #pragma unroll
            for (int ni = 0; ni < 4; ++ni)
                acc[4 + mi][ni] = __builtin_amdgcn_mfma_f32_16x16x32_bf16(
                    av[mi], bv0[ni], acc[4 + mi][ni], 0, 0, 0);
        __builtin_amdgcn_s_setprio(0);

        // ---- P4: A-h1 kh1 reads (B kh1 reg-reused); stage A1,A3; vmcnt(2);
        //      bar (= tile-start t+1, publishes B0-3,A0,A2); 16 MFMA ----
        #pragma unroll
        for (int i = 0; i < 4; ++i) av[i] = *(const bf16x8*)(cb + offA[4 + i] + kb1);
        if (doStage) {
            gload_lds16(A + aBase +  64u * KDIM + tOff, sb +  8192 + dstOff);  // A1
            gload_lds16(A + aBase + 192u * KDIM + tOff, sb + 24576 + dstOff);  // A3
            VMCNT2();
        }
        barrier_raw();
        LGKM0();
        __builtin_amdgcn_s_setprio(1);
        #pragma unroll
        for (int mi = 0; mi < 4; ++mi)
            #pragma unroll
            for (int ni = 0; ni < 4; ++ni)
                acc[4 + mi][ni] = __builtin_amdgcn_mfma_f32_16x16x32_bf16(
                    av[mi], bv1[ni], acc[4 + mi][ni], 0, 0, 0);
        __builtin_amdgcn_s_setprio(0);
    }

    // epilogue: C/D frag mapping col = lane&15, row = (lane>>4)*4 + reg
    constexpr uint N = (uint)NBLKN * 256u;
    #pragma unroll
    for (int mi = 0; mi < 8; ++mi) {
        #pragma unroll
        for (int j = 0; j < 4; ++j) {
            const uint gr = m0 + (uint)(wm * 128 + mi * 16 + lk * 4 + j);
            float s = 0.f;
            if (EPI == 1) s = rowscale[gr];
            #pragma unroll
            for (int ni = 0; ni < 4; ++ni) {
                const uint gc = n0 + (uint)(wn * 64 + ni * 16 + lr);
                float v = acc[mi][ni][j];
                if (EPI == 0) {
                    Cbf[gr * N + gc] = f2bf(gelu_fast(v));
                } else {
                    Cf[gr * N + gc] = v * s;
                }
            }
        }
    }
}

// ---------------------------------------------------------------------------
extern "C" void kernel_launch(void* const* d_in, const int* in_sizes, int n_in,
                              void* d_out, int out_size, void* d_ws, size_t ws_size,
                              hipStream_t stream) {
    const float* x    = (const float*)d_in[0];
    const float* w_up = (const float*)d_in[1];
    const float* w_dn = (const float*)d_in[2];
    float* out = (float*)d_out;

    uint8_t* ws = (uint8_t*)d_ws;
    unsigned short* h   = (unsigned short*)(ws);                       // 128 MB
    unsigned short* xn  = (unsigned short*)(ws + 134217728);           // 32 MB
    unsigned short* wqu = (unsigned short*)(ws + 134217728 + 33554432);
    unsigned short* wqd = (unsigned short*)(ws + 134217728 + 33554432 + 8388608);
    float*  rs   = (float*)(ws + 134217728 + 33554432 + 2 * 8388608);
    double* alph = (double*)(ws + 134217728 + 33554432 + 2 * 8388608 + 65536);

    hipMemsetAsync(alph, 0, 16, stream);

    absmean_reduce<<<256, 256, 0, stream>>>(w_up, alph + 0);
    absmean_reduce<<<256, 256, 0, stream>>>(w_dn, alph + 1);
    quant_kernel<<<NW / 1024, 256, 0, stream>>>(w_up, alph + 0, wqu);
    quant_kernel<<<NW / 1024, 256, 0, stream>>>(w_dn, alph + 1, wqd);
    rmsnorm_x<<<M_ROWS, 256, 0, stream>>>(x, xn);

    // L1: h = gelu(xn @ wqu^T)  [16384 x 4096], K=1024 -> 64x16 = 1024 blocks
    gemm4p<0, D_MODEL, 16><<<1024, 512, 0, stream>>>(
        xn, wqu, h, nullptr, nullptr, 1024);

    rowscale_h<<<M_ROWS, 256, 0, stream>>>(h, rs);

    // L2: out = (h @ wqd^T) * rs[m]  [16384 x 1024], K=4096 -> 64x4 = 256 blocks
    gemm4p<1, D_FF, 4><<<256, 512, 0, stream>>>(
        h, wqd, nullptr, out, rs, 256);
}